// Round 1
// baseline (4455.924 us; speedup 1.0000x reference)
//
#include <hip/hip_runtime.h>
#include <math.h>

namespace {

constexpr int B_ = 2, D_ = 2048, S_ = 128, A_ = 1536, T_ = 512;
constexpr int HQ_ = 16, HKV_ = 4, HD_ = 128, FF_ = 8192, L_ = 2;
constexpr float NEG_ = -30000.0f, EPS_ = 1e-5f;
constexpr int TOK_ = B_ * S_;  // 256 tokens

// ---------------- RMSNorm ----------------
// pass 1: rsum[b,s] += sum_d x[b,d,s]^2 (grid: (16, B), block 256)
__global__ __launch_bounds__(256) void rms_sumsq(const float* __restrict__ x,
                                                 float* __restrict__ rsum) {
  int b = blockIdx.y, c = blockIdx.x;
  int tid = threadIdx.x;
  int s = tid & 127, dd = tid >> 7;
  const float* xp = x + ((size_t)b * D_ + c * 128) * S_ + s;
  float acc = 0.f;
  for (int d = dd; d < 128; d += 2) {
    float v = xp[(size_t)d * S_];
    acc += v * v;
  }
  __shared__ float lds[256];
  lds[tid] = acc;
  __syncthreads();
  if (dd == 0) atomicAdd(&rsum[b * S_ + s], lds[s] + lds[128 + s]);
}

// pass 2: out[b,d,s] = x * rsqrt(mean + eps) * w[d]
__global__ __launch_bounds__(256) void rms_apply(const float* __restrict__ x,
                                                 const float* __restrict__ rsum,
                                                 const float* __restrict__ w,
                                                 float* __restrict__ out) {
  int i = blockIdx.x * 256 + threadIdx.x;
  int s = i & (S_ - 1);
  int d = (i / S_) & (D_ - 1);
  int b = i / (D_ * S_);
  float inv = rsqrtf(rsum[b * S_ + s] * (1.0f / D_) + EPS_);
  out[i] = x[i] * inv * w[d];
}

// ---------------- GEMM (fp32, round-0 baseline) ----------------
// C[b, m, s] (+)= sum_k W[k*M + m] * H[b, k, s]
// grid (M/64, TOK/64), block 256, BK=16
__global__ __launch_bounds__(256) void gemm_f32(const float* __restrict__ Wm,
                                                const float* __restrict__ Hm,
                                                float* __restrict__ Out, int M, int K,
                                                int accum) {
  __shared__ float Ws[16][64];
  __shared__ float Hs[16][64];
  int m0 = blockIdx.x * 64;
  int t0 = blockIdx.y * 64;
  int b = t0 >> 7;        // 64-token tile never straddles batch (S=128)
  int sbase = t0 & 127;
  int tid = threadIdx.x;
  int tx = tid & 15, ty = tid >> 4;
  int lk = tid >> 4, lm = (tid & 15) * 4;
  const float* Wp = Wm + m0;
  const float* Hp = Hm + (size_t)b * K * S_ + sbase;
  float acc[4][4] = {};
  for (int k0 = 0; k0 < K; k0 += 16) {
    float4 wv = *(const float4*)&Wp[(size_t)(k0 + lk) * M + lm];
    float4 hv = *(const float4*)&Hp[(size_t)(k0 + lk) * S_ + lm];
    *(float4*)&Ws[lk][lm] = wv;
    *(float4*)&Hs[lk][lm] = hv;
    __syncthreads();
#pragma unroll
    for (int kk = 0; kk < 16; kk++) {
      float4 av = *(const float4*)&Ws[kk][ty * 4];
      float4 bv = *(const float4*)&Hs[kk][tx * 4];
      const float* ap = (const float*)&av;
      const float* bp = (const float*)&bv;
#pragma unroll
      for (int im = 0; im < 4; im++)
#pragma unroll
        for (int it = 0; it < 4; it++) acc[im][it] += ap[im] * bp[it];
    }
    __syncthreads();
  }
#pragma unroll
  for (int im = 0; im < 4; im++) {
    int m = m0 + ty * 4 + im;
    size_t o = ((size_t)b * M + m) * S_ + sbase + tx * 4;
    float4 res;
    res.x = acc[im][0]; res.y = acc[im][1]; res.z = acc[im][2]; res.w = acc[im][3];
    if (accum) {
      float4 old = *(const float4*)&Out[o];
      res.x += old.x; res.y += old.y; res.z += old.z; res.w += old.w;
    }
    *(float4*)&Out[o] = res;
  }
}

// ---------------- RoPE ----------------
__device__ __forceinline__ void rope_angles(int pos, int i, float& sn, float& cs) {
  float inv_freq = powf(10000.0f, -(float)i * (1.0f / 64.0f));
  float ang = (float)pos * inv_freq;
  sn = sinf(ang);
  cs = cosf(ang);
}

// in-place RoPE on (B, 16*128, S) buffer; idx = ((b*16+h)*64 + i)*128 + s
__global__ __launch_bounds__(256) void rope_q(float* __restrict__ q,
                                              const int* __restrict__ positions) {
  int idx = blockIdx.x * 256 + threadIdx.x;
  int s = idx & 127;
  int i = (idx >> 7) & 63;
  int b = idx >> 17;
  float sn, cs;
  rope_angles(positions[b * S_ + s], i, sn, cs);
  size_t o1 = (size_t)(idx >> 13) * (128 * S_) + (size_t)i * S_ + s;
  float x1 = q[o1], x2 = q[o1 + 64 * S_];
  q[o1] = x1 * cs - x2 * sn;
  q[o1 + 64 * S_] = x2 * cs + x1 * sn;
}

// RoPE k and scatter into k_cache[(l*B+b), kv, w+s, hd]; idx = ((b*4+kv)*128+s)*64+i
__global__ __launch_bounds__(256) void rope_k_store(const float* __restrict__ kbuf,
                                                    const int* __restrict__ positions,
                                                    const int* __restrict__ wptr,
                                                    float* __restrict__ k_cache, int l) {
  int idx = blockIdx.x * 256 + threadIdx.x;
  int i = idx & 63;
  int s = (idx >> 6) & 127;
  int kv = (idx >> 13) & 3;
  int b = idx >> 15;
  int w = wptr[0];
  float sn, cs;
  rope_angles(positions[b * S_ + s], i, sn, cs);
  size_t i1 = ((size_t)(b * HKV_ + kv) * HD_ + i) * S_ + s;
  float x1 = kbuf[i1], x2 = kbuf[i1 + 64 * S_];
  size_t o = ((size_t)((l * B_ + b) * HKV_ + kv) * A_ + (w + s)) * HD_ + i;
  k_cache[o] = x1 * cs - x2 * sn;
  k_cache[o + 64] = x2 * cs + x1 * sn;
}

// v_cache[(l*B+b), kv, hd, w+s] = v[b, kv*128+hd, s]; idx = ((b*4+kv)*128+hd)*128+s
__global__ __launch_bounds__(256) void store_v(const float* __restrict__ vbuf,
                                               const int* __restrict__ wptr,
                                               float* __restrict__ v_cache, int l) {
  int idx = blockIdx.x * 256 + threadIdx.x;
  int s = idx & 127;
  int hd = (idx >> 7) & 127;
  int kv = (idx >> 14) & 3;
  int b = idx >> 16;
  int w = wptr[0];
  v_cache[((size_t)((l * B_ + b) * HKV_ + kv) * HD_ + hd) * A_ + w + s] = vbuf[idx];
}

// ---------------- Attention ----------------
// P[bh, s, a] = scale * sum_hd key[a,hd]*q[hd,s] + mask   (row stride T_=512)
// mode 0: self (mask array, Aeff = w+S);  mode 1: cross (enc-len mask, Aeff = T)
// grid (AN/32 capped at 16, B*16), block 256
__global__ __launch_bounds__(256) void attn_scores(
    const float* __restrict__ key, const float* __restrict__ q, float* __restrict__ P,
    const float* __restrict__ maskArr, const int* __restrict__ encLen,
    const int* __restrict__ wptr, float scale, int gshift, int AN, int mode) {
  int bh = blockIdx.y;
  int b = bh >> 4, h = bh & 15;
  int kvh = h >> gshift;
  int nkv = 16 >> gshift;
  int a0 = blockIdx.x * 32;
  int Aeff = (mode == 0) ? (wptr[0] + S_) : T_;
  if (a0 >= Aeff) return;
  int tid = threadIdx.x;
  int s = tid & 127, ah = tid >> 7;
  __shared__ float qs[32][128];
  __shared__ float ks[32][32];
  float acc[16];
#pragma unroll
  for (int j = 0; j < 16; j++) acc[j] = 0.f;
  const float* kbase = key + (size_t)(b * nkv + kvh) * AN * HD_;
  const float* qbase = q + (size_t)bh * HD_ * S_;
  for (int hc = 0; hc < HD_; hc += 32) {
    for (int i = tid; i < 32 * 128; i += 256) {
      int c = i >> 7, ss = i & 127;
      qs[c][ss] = qbase[(size_t)(hc + c) * S_ + ss];
    }
    for (int i = tid; i < 32 * 32; i += 256) {
      int aj = i >> 5, c = i & 31;
      int a = a0 + aj;
      ks[aj][c] = (a < Aeff) ? kbase[(size_t)a * HD_ + hc + c] : 0.f;
    }
    __syncthreads();
#pragma unroll
    for (int j = 0; j < 16; j++) {
      int aj = ah + 2 * j;
      float sum = 0.f;
#pragma unroll
      for (int c = 0; c < 32; c++) sum += ks[aj][c] * qs[c][s];
      acc[j] += sum;
    }
    __syncthreads();
  }
  for (int j = 0; j < 16; j++) {
    int a = a0 + ah + 2 * j;
    if (a < Aeff) {
      float mval;
      if (mode == 0)
        mval = maskArr[((size_t)b * S_ + s) * A_ + a];
      else
        mval = (a < encLen[b]) ? 0.f : NEG_;
      P[((size_t)bh * S_ + s) * T_ + a] = acc[j] * scale + mval;
    }
  }
}

// row-wise softmax over a < Aeff; grid B*16*S blocks, 128 threads
__global__ __launch_bounds__(128) void softmax_rows(float* __restrict__ P,
                                                    const int* __restrict__ wptr,
                                                    int mode) {
  int row = blockIdx.x;
  int Aeff = (mode == 0) ? (wptr[0] + S_) : T_;
  float* p = P + (size_t)row * T_;
  int tid = threadIdx.x;
  float v[4];
  int cnt = 0;
  float m = -1e30f;
  for (int a = tid; a < Aeff; a += 128) {
    float t = p[a];
    v[cnt++] = t;
    m = fmaxf(m, t);
  }
  __shared__ float r0[2], r1[2];
  for (int off = 32; off > 0; off >>= 1) m = fmaxf(m, __shfl_down(m, off));
  if ((tid & 63) == 0) r0[tid >> 6] = m;
  __syncthreads();
  m = fmaxf(r0[0], r0[1]);
  float sum = 0.f;
  for (int i = 0; i < cnt; i++) {
    v[i] = expf(v[i] - m);
    sum += v[i];
  }
  for (int off = 32; off > 0; off >>= 1) sum += __shfl_down(sum, off);
  if ((tid & 63) == 0) r1[tid >> 6] = sum;
  __syncthreads();
  float inv = 1.f / (r1[0] + r1[1]);
  cnt = 0;
  for (int a = tid; a < Aeff; a += 128) p[a] = v[cnt++] * inv;
}

// out[bh*128+hd, s] = sum_a val[hd, a] * P[bh, s, a]; grid (4, B*16), block 256
__global__ __launch_bounds__(256) void attn_pv(const float* __restrict__ val,
                                               const float* __restrict__ P,
                                               float* __restrict__ out,
                                               const int* __restrict__ wptr, int gshift,
                                               int AN, int mode) {
  int bh = blockIdx.y;
  int b = bh >> 4, h = bh & 15;
  int kvh = h >> gshift, nkv = 16 >> gshift;
  int hd0 = blockIdx.x * 32;
  int Aeff = (mode == 0) ? (wptr[0] + S_) : T_;
  int tid = threadIdx.x;
  int s = tid & 127, hh = tid >> 7;
  __shared__ float ps[32][128];
  __shared__ float vs[32][32];
  float acc[16];
#pragma unroll
  for (int j = 0; j < 16; j++) acc[j] = 0.f;
  const float* vbase = val + (size_t)(b * nkv + kvh) * HD_ * AN;
  const float* Pb = P + (size_t)bh * S_ * T_;
  for (int a0 = 0; a0 < Aeff; a0 += 32) {
    for (int i = tid; i < 32 * 128; i += 256) {
      int ss = i >> 5, aj = i & 31;
      int a = a0 + aj;
      ps[aj][ss] = (a < Aeff) ? Pb[(size_t)ss * T_ + a] : 0.f;
    }
    for (int i = tid; i < 32 * 32; i += 256) {
      int c = i >> 5, aj = i & 31;
      vs[c][aj] = vbase[(size_t)(hd0 + c) * AN + a0 + aj];
    }
    __syncthreads();
#pragma unroll
    for (int j = 0; j < 16; j++) {
      int c = hh + 2 * j;
      float sum = 0.f;
#pragma unroll
      for (int aj = 0; aj < 32; aj++) sum += vs[c][aj] * ps[aj][s];
      acc[j] += sum;
    }
    __syncthreads();
  }
#pragma unroll
  for (int j = 0; j < 16; j++) {
    int hd = hd0 + hh + 2 * j;
    out[((size_t)bh * HD_ + hd) * S_ + s] = acc[j];
  }
}

// gate = silu(gate) * up
__global__ __launch_bounds__(256) void silu_mul(float* __restrict__ gate,
                                                const float* __restrict__ up) {
  int i = blockIdx.x * 256 + threadIdx.x;
  float g = gate[i];
  gate[i] = g / (1.f + expf(-g)) * up[i];
}

}  // namespace

extern "C" void kernel_launch(void* const* d_in, const int* in_sizes, int n_in,
                              void* d_out, int out_size, void* d_ws, size_t ws_size,
                              hipStream_t stream) {
  const float* x_in = (const float*)d_in[0];
  const int* positions = (const int*)d_in[1];
  const int* wptr = (const int*)d_in[2];
  const float* maskArr = (const float*)d_in[3];
  const int* encLen = (const int*)d_in[4];
  const float* q_w = (const float*)d_in[5];
  const float* k_w = (const float*)d_in[6];
  const float* v_w = (const float*)d_in[7];
  const float* o_w = (const float*)d_in[8];
  const float* cq_w = (const float*)d_in[9];
  const float* co_w = (const float*)d_in[10];
  const float* sa_norm = (const float*)d_in[11];
  const float* ca_norm = (const float*)d_in[12];
  const float* mlp_norm = (const float*)d_in[13];
  const float* fin_norm = (const float*)d_in[14];
  const float* wg_w = (const float*)d_in[15];
  const float* wu_w = (const float*)d_in[16];
  const float* wd_w = (const float*)d_in[17];
  float* k_cache = (float*)d_in[18];
  float* v_cache = (float*)d_in[19];
  const float* ck_cache = (const float*)d_in[20];
  const float* cv_cache = (const float*)d_in[21];
  float* out = (float*)d_out;

  float* ws = (float*)d_ws;
  const size_t BDS = (size_t)B_ * D_ * S_;        // 524288
  float* X = ws;                                   // (B,D,S)
  float* Hb = X + BDS;                             // normalized activations
  float* Q = Hb + BDS;                             // q / cq (B,2048,S)
  float* Attn = Q + BDS;                           // attention output (B,2048,S)
  float* Kb = Attn + BDS;                          // (B,512,S)
  float* Vb = Kb + (size_t)B_ * 512 * S_;          // (B,512,S)
  float* Pbuf = Vb + (size_t)B_ * 512 * S_;        // scores (B*16,S,512) / gate (B,FF,S)
  float* Up = Pbuf + (size_t)B_ * 16 * S_ * T_;    // up (B,FF,S)
  float* Rsum = Up + (size_t)B_ * FF_ * S_;        // (B,S)

  const float scale = 0.08838834764831845f;  // 1/sqrt(128), HD == HDC

  hipMemcpyAsync(X, x_in, BDS * sizeof(float), hipMemcpyDeviceToDevice, stream);

  auto rms = [&](const float* src, const float* w, float* dst) {
    hipMemsetAsync(Rsum, 0, B_ * S_ * sizeof(float), stream);
    rms_sumsq<<<dim3(16, B_), 256, 0, stream>>>(src, Rsum);
    rms_apply<<<dim3(B_ * D_ * S_ / 256), 256, 0, stream>>>(src, Rsum, w, dst);
  };

  for (int l = 0; l < L_; l++) {
    // ---- self attention ----
    rms(X, sa_norm + (size_t)l * D_, Hb);
    gemm_f32<<<dim3(2048 / 64, TOK_ / 64), 256, 0, stream>>>(
        q_w + (size_t)l * D_ * 2048, Hb, Q, 2048, D_, 0);
    gemm_f32<<<dim3(512 / 64, TOK_ / 64), 256, 0, stream>>>(
        k_w + (size_t)l * D_ * 512, Hb, Kb, 512, D_, 0);
    gemm_f32<<<dim3(512 / 64, TOK_ / 64), 256, 0, stream>>>(
        v_w + (size_t)l * D_ * 512, Hb, Vb, 512, D_, 0);
    rope_q<<<dim3(B_ * 16 * 64 * S_ / 256), 256, 0, stream>>>(Q, positions);
    rope_k_store<<<dim3(B_ * 4 * S_ * 64 / 256), 256, 0, stream>>>(Kb, positions, wptr,
                                                                   k_cache, l);
    store_v<<<dim3(B_ * 4 * 128 * S_ / 256), 256, 0, stream>>>(Vb, wptr, v_cache, l);
    attn_scores<<<dim3(16, 32), 256, 0, stream>>>(
        k_cache + (size_t)l * B_ * HKV_ * A_ * HD_, Q, Pbuf, maskArr, encLen, wptr,
        scale, 2, A_, 0);
    softmax_rows<<<dim3(B_ * 16 * S_), 128, 0, stream>>>(Pbuf, wptr, 0);
    attn_pv<<<dim3(4, 32), 256, 0, stream>>>(
        v_cache + (size_t)l * B_ * HKV_ * HD_ * A_, Pbuf, Attn, wptr, 2, A_, 0);
    gemm_f32<<<dim3(2048 / 64, TOK_ / 64), 256, 0, stream>>>(
        o_w + (size_t)l * 2048 * D_, Attn, X, D_, 2048, 1);
    // ---- cross attention ----
    rms(X, ca_norm + (size_t)l * D_, Hb);
    gemm_f32<<<dim3(2048 / 64, TOK_ / 64), 256, 0, stream>>>(
        cq_w + (size_t)l * D_ * 2048, Hb, Q, 2048, D_, 0);
    rope_q<<<dim3(B_ * 16 * 64 * S_ / 256), 256, 0, stream>>>(Q, positions);
    attn_scores<<<dim3(16, 32), 256, 0, stream>>>(
        ck_cache + (size_t)l * B_ * 16 * T_ * HD_, Q, Pbuf, maskArr, encLen, wptr,
        scale, 0, T_, 1);
    softmax_rows<<<dim3(B_ * 16 * S_), 128, 0, stream>>>(Pbuf, wptr, 1);
    attn_pv<<<dim3(4, 32), 256, 0, stream>>>(
        cv_cache + (size_t)l * B_ * 16 * HD_ * T_, Pbuf, Attn, wptr, 0, T_, 1);
    gemm_f32<<<dim3(2048 / 64, TOK_ / 64), 256, 0, stream>>>(
        co_w + (size_t)l * 2048 * D_, Attn, X, D_, 2048, 1);
    // ---- MLP ----
    rms(X, mlp_norm + (size_t)l * D_, Hb);
    gemm_f32<<<dim3(FF_ / 64, TOK_ / 64), 256, 0, stream>>>(
        wg_w + (size_t)l * D_ * FF_, Hb, Pbuf, FF_, D_, 0);
    gemm_f32<<<dim3(FF_ / 64, TOK_ / 64), 256, 0, stream>>>(
        wu_w + (size_t)l * D_ * FF_, Hb, Up, FF_, D_, 0);
    silu_mul<<<dim3(B_ * FF_ * S_ / 256), 256, 0, stream>>>(Pbuf, Up);
    gemm_f32<<<dim3(D_ / 64, TOK_ / 64), 256, 0, stream>>>(
        wd_w + (size_t)l * FF_ * D_, Pbuf, X, D_, FF_, 1);
  }
  // ---- final norm -> d_out ----
  rms(X, fin_norm, out);
}